// Round 8
// baseline (118.322 us; speedup 1.0000x reference)
//
#include <hip/hip_runtime.h>

#define NC 65
#define NCELL 274625
#define NE 19
#define NF 8
#define LSTR 11    // per-cell LDS stride: [0..7]=sdf corners, [8]=ins, [9]=ijk, [10] pad

// MT_TRI rows packed 4 bits per entry (0xF == -1), entry v at bits [4v,4v+4)
__constant__ unsigned MTP[16] = {
    0x00FFFFFFu, 0x00FFF210u, 0x00FFF430u, 0x00341421u,
    0x00FFF531u, 0x00350520u, 0x00450510u, 0x00FFF542u,
    0x00FFF542u, 0x00450510u, 0x00250530u, 0x00FFF531u,
    0x00241431u, 0x00FFF430u, 0x00FFF210u, 0x00FFFFFFu
};
// T2C rows packed 5 bits per entry: entry e at bits [5e,5e+5)
__constant__ unsigned T2CPc[6] = {
    0x0A418820u, 0x105388C1u, 0x16850926u,
    0x1CB68989u, 0x22E809ECu, 0x0919080Fu
};
// cell-edge endpoints (reference discovery order)
__device__ constexpr int EA[NE] = {0,0,0,1,1,3,0,2,2,0,2,6,0,4,4,0,4,5,1};
__device__ constexpr int EB[NE] = {1,3,7,3,7,7,2,3,7,6,6,7,4,6,7,5,5,7,5};
// Bit-packed (3 bits per edge); verified entry-by-entry.
#define EAP 0x006C120C82419200ULL
#define EBP 0x017DBF4FB76BF7D9ULL
// Tets: corner0=0, corner3=7 for all tets; (c1 | c2<<3) at bits [6ti,6ti+6)
#define TETP 0x36C9B24D9ULL

typedef float float4u __attribute__((ext_vector_type(4), aligned(4)));
typedef float float2u __attribute__((ext_vector_type(2), aligned(4)));

extern "C" __global__ void __launch_bounds__(256, 4)
diffmc_kernel(const float* __restrict__ sdf, const float* __restrict__ feat,
              float* __restrict__ oV, float* __restrict__ oF, float* __restrict__ oT)
{
    __shared__ float lds[256 * LSTR];   // 11264 B
    const int tid = threadIdx.x;
    const int blockBase = blockIdx.x << 8;
    int vc = NCELL - blockBase;
    vc = vc > 256 ? 256 : vc;

    // ---------------- phase 0: per-cell corner sdf + meta ----------------
    if (tid < vc) {
        const int cell = blockBase + tid;
        const int k  = cell % NC;
        const int t_ = cell / NC;
        const int j  = t_ % NC;
        const int i  = t_ / NC;
        float cs[8];
#pragma unroll
        for (int c = 0; c < 8; ++c) {
            int x = i + (c & 1) - 1;
            int y = j + ((c >> 1) & 1) - 1;
            int z = k + ((c >> 2) & 1) - 1;
            bool inb = ((unsigned)x < 64u) & ((unsigned)y < 64u) & ((unsigned)z < 64u);
            cs[c] = inb ? sdf[(x * 64 + y) * 64 + z] : 1.0f;   // pad = iso + 1
        }
        unsigned ins = 0;
#pragma unroll
        for (int c = 0; c < 8; ++c) ins |= (cs[c] < 0.0f ? 1u : 0u) << c;
        float* Ld = lds + tid * LSTR;
#pragma unroll
        for (int c = 0; c < 8; ++c) Ld[c] = cs[c];
        Ld[8] = __uint_as_float(ins);
        Ld[9] = __uint_as_float((unsigned)i | ((unsigned)j << 7) | ((unsigned)k << 14));
    }
    __syncthreads();

    const float inv63 = 1.0f / 63.0f;
    const int nE = vc * NE;
    const int nT = vc * 6;

    // -------- fused verts+feats: 19 guarded (no break) iterations ---------
    {
        float* __restrict__ dV = oV + (size_t)blockBase * 57;
        float* __restrict__ dF = oF + (size_t)blockBase * 152;
#pragma unroll 2
        for (int rr = 0; rr < 19; ++rr) {
            const int E = tid + (rr << 8);
            if (E < nE) {
                const unsigned c = (unsigned)E / 19u;
                const unsigned e = (unsigned)E - c * 19u;
                const float* Ld = lds + c * LSTR;
                const unsigned meta = __float_as_uint(Ld[9]);
                const unsigned ii = meta & 127u;
                const unsigned jj = (meta >> 7) & 127u;
                const unsigned kk = (meta >> 14) & 127u;
                const unsigned a = (unsigned)(EAP >> (3u * e)) & 7u;
                const unsigned b = (unsigned)(EBP >> (3u * e)) & 7u;
                const float sa = Ld[a], sb = Ld[b];
                const bool cross = (sa < 0.0f) != (sb < 0.0f);
                const float t = cross ? sa / (sa - sb) : 0.0f;   // == (0-sa)/(sb-sa)

                // verts: where(cross, lerp, 0) THEN (v-1)/63 (reference order)
                const float pax = (float)(int)(ii + (a & 1u));
                const float pbx = (float)(int)(ii + (b & 1u));
                const float pay = (float)(int)(jj + ((a >> 1) & 1u));
                const float pby = (float)(int)(jj + ((b >> 1) & 1u));
                const float paz = (float)(int)(kk + ((a >> 2) & 1u));
                const float pbz = (float)(int)(kk + ((b >> 2) & 1u));
                const float vx = cross ? pax + t * (pbx - pax) : 0.0f;
                const float vy = cross ? pay + t * (pby - pay) : 0.0f;
                const float vz = cross ? paz + t * (pbz - paz) : 0.0f;
                const size_t vo = (size_t)E * 3u;
                __builtin_nontemporal_store((vx - 1.0f) * inv63, dV + vo + 0);
                __builtin_nontemporal_store((vy - 1.0f) * inv63, dV + vo + 1);
                __builtin_nontemporal_store((vz - 1.0f) * inv63, dV + vo + 2);

                // feats: gather the two corners' 8 floats, lerp
                const int xa = (int)ii + (int)(a & 1u) - 1;
                const int ya = (int)jj + (int)((a >> 1) & 1u) - 1;
                const int za = (int)kk + (int)((a >> 2) & 1u) - 1;
                const int xb = (int)ii + (int)(b & 1u) - 1;
                const int yb = (int)jj + (int)((b >> 1) & 1u) - 1;
                const int zb = (int)kk + (int)((b >> 2) & 1u) - 1;
                const bool iba = ((unsigned)xa < 64u) & ((unsigned)ya < 64u) & ((unsigned)za < 64u);
                const bool ibb = ((unsigned)xb < 64u) & ((unsigned)yb < 64u) & ((unsigned)zb < 64u);
                float4 fa0 = make_float4(0.f, 0.f, 0.f, 0.f), fa1 = fa0;
                float4 fb0 = fa0, fb1 = fa0;
                if (iba) {
                    const float4* fp = (const float4*)(feat + (size_t)((xa * 64 + ya) * 64 + za) * NF);
                    fa0 = fp[0]; fa1 = fp[1];
                }
                if (ibb) {
                    const float4* fp = (const float4*)(feat + (size_t)((xb * 64 + yb) * 64 + zb) * NF);
                    fb0 = fp[0]; fb1 = fp[1];
                }
                float4u flo, fhi;
                flo.x = cross ? fa0.x + t * (fb0.x - fa0.x) : 0.0f;
                flo.y = cross ? fa0.y + t * (fb0.y - fa0.y) : 0.0f;
                flo.z = cross ? fa0.z + t * (fb0.z - fa0.z) : 0.0f;
                flo.w = cross ? fa0.w + t * (fb0.w - fa0.w) : 0.0f;
                fhi.x = cross ? fa1.x + t * (fb1.x - fa1.x) : 0.0f;
                fhi.y = cross ? fa1.y + t * (fb1.y - fa1.y) : 0.0f;
                fhi.z = cross ? fa1.z + t * (fb1.z - fa1.z) : 0.0f;
                fhi.w = cross ? fa1.w + t * (fb1.w - fa1.w) : 0.0f;
                const size_t fo = (size_t)E * 8u;
                __builtin_nontemporal_store(flo, (float4u*)(dF + fo));
                __builtin_nontemporal_store(fhi, (float4u*)(dF + fo + 4));
            }
        }
    }

    // ---------------- tris: 6 guarded iterations ----------------
    {
        float* __restrict__ dT = oT + (size_t)blockBase * 36;
#pragma unroll 2
        for (int rr = 0; rr < 6; ++rr) {
            const int T = tid + (rr << 8);
            if (T < nT) {
                const unsigned c  = (unsigned)T / 6u;
                const unsigned ti = (unsigned)T - c * 6u;
                const unsigned ins = __float_as_uint(lds[c * LSTR + 8]);
                const unsigned tc = (unsigned)(TETP >> (6u * ti)) & 63u;
                const unsigned c1 = tc & 7u, c2 = tc >> 3;
                const unsigned cse = (ins & 1u)
                                   | (((ins >> c1) & 1u) << 1)
                                   | (((ins >> c2) & 1u) << 2)
                                   | (((ins >> 7) & 1u) << 3);
                const unsigned m  = MTP[cse];
                const unsigned tp = T2CPc[ti];
                const int cell19 = (blockBase + (int)c) * 19;
                float v6[6];
#pragma unroll
                for (int v = 0; v < 6; ++v) {
                    const unsigned lt = (m >> (4 * v)) & 0xFu;
                    const unsigned lc = (lt == 15u) ? 0u : lt;
                    const unsigned ce = (tp >> (5 * lc)) & 31u;
                    v6[v] = (lt == 15u) ? -1.0f : (float)(cell19 + (int)ce);
                }
                const size_t to = (size_t)T * 6u;
                float4u q0; q0.x = v6[0]; q0.y = v6[1]; q0.z = v6[2]; q0.w = v6[3];
                float2u q1; q1.x = v6[4]; q1.y = v6[5];
                __builtin_nontemporal_store(q0, (float4u*)(dT + to));
                __builtin_nontemporal_store(q1, (float2u*)(dT + to + 4));
            }
        }
    }
}

extern "C" void kernel_launch(void* const* d_in, const int* in_sizes, int n_in,
                              void* d_out, int out_size, void* d_ws, size_t ws_size,
                              hipStream_t stream) {
    const float* sdf  = (const float*)d_in[0];
    const float* feat = (const float*)d_in[1];
    float* out = (float*)d_out;
    float* oV = out;
    float* oF = oV + (size_t)NCELL * NE * 3;
    float* oT = oF + (size_t)NCELL * NE * NF;
    int blocks = (NCELL + 255) / 256;
    diffmc_kernel<<<blocks, 256, 0, stream>>>(sdf, feat, oV, oF, oT);
}

// Round 9
// 62.044 us; speedup vs baseline: 1.9071x; 1.9071x over previous
//
#include <hip/hip_runtime.h>

#define NC 65
#define NCELL 274625
#define NE 19
#define NF 8
#define LSTR 11    // per-cell state stride: [0..7]=sdf corners, [8]=ins, [9]=ijk, [10] pad
#define CSUB 64    // cells per feat-staging sub-phase

// MT_TRI rows packed 4 bits per entry (0xF == -1), entry v at bits [4v,4v+4)
__constant__ unsigned MTP[16] = {
    0x00FFFFFFu, 0x00FFF210u, 0x00FFF430u, 0x00341421u,
    0x00FFF531u, 0x00350520u, 0x00450510u, 0x00FFF542u,
    0x00FFF542u, 0x00450510u, 0x00250530u, 0x00FFF531u,
    0x00241431u, 0x00FFF430u, 0x00FFF210u, 0x00FFFFFFu
};
// T2C rows packed 5 bits per entry: entry e at bits [5e,5e+5)
__constant__ unsigned T2CPc[6] = {
    0x0A418820u, 0x105388C1u, 0x16850926u,
    0x1CB68989u, 0x22E809ECu, 0x0919080Fu
};
// cell-edge endpoints (reference discovery order)
__device__ constexpr int EA[NE] = {0,0,0,1,1,3,0,2,2,0,2,6,0,4,4,0,4,5,1};
__device__ constexpr int EB[NE] = {1,3,7,3,7,7,2,3,7,6,6,7,4,6,7,5,5,7,5};
// Bit-packed (3 bits per edge); verified entry-by-entry.
#define EAP 0x006C120C82419200ULL
#define EBP 0x017DBF4FB76BF7D9ULL
// Tets: corner0=0, corner3=7 for all tets; (c1 | c2<<3) at bits [6ti,6ti+6)
#define TETP 0x36C9B24D9ULL

typedef float float4u __attribute__((ext_vector_type(4), aligned(4)));
typedef float float2u __attribute__((ext_vector_type(2), aligned(4)));

extern "C" __global__ void __launch_bounds__(256, 3)
diffmc_kernel(const float* __restrict__ sdf, const float* __restrict__ feat,
              float* __restrict__ oV, float* __restrict__ oF, float* __restrict__ oT)
{
    __shared__ float state[256 * LSTR];            // 11264 B
    __shared__ float stage[CSUB * NE * NF];        // 9728 dwords = 38912 B
    float4u* stage4 = (float4u*)stage;

    const int tid = threadIdx.x;
    const int blockBase = blockIdx.x << 8;
    int vc = NCELL - blockBase;
    vc = vc > 256 ? 256 : vc;

    // ---------------- phase 0: per-cell corner sdf + meta ----------------
    if (tid < vc) {
        const int cell = blockBase + tid;
        const int k  = cell % NC;
        const int t_ = cell / NC;
        const int j  = t_ % NC;
        const int i  = t_ / NC;
        float cs[8];
#pragma unroll
        for (int c = 0; c < 8; ++c) {
            int x = i + (c & 1) - 1;
            int y = j + ((c >> 1) & 1) - 1;
            int z = k + ((c >> 2) & 1) - 1;
            bool inb = ((unsigned)x < 64u) & ((unsigned)y < 64u) & ((unsigned)z < 64u);
            cs[c] = inb ? sdf[(x * 64 + y) * 64 + z] : 1.0f;   // pad = iso + 1
        }
        unsigned ins = 0;
#pragma unroll
        for (int c = 0; c < 8; ++c) ins |= (cs[c] < 0.0f ? 1u : 0u) << c;
        float* Ld = state + tid * LSTR;
#pragma unroll
        for (int c = 0; c < 8; ++c) Ld[c] = cs[c];
        Ld[8] = __uint_as_float(ins);
        Ld[9] = __uint_as_float((unsigned)i | ((unsigned)j << 7) | ((unsigned)k << 14));
    }
    __syncthreads();

    const float inv63 = 1.0f / 63.0f;

    // ======= 4 sub-phases of 64 cells: compute (verts direct, feats->LDS),
    // ======= then dense float4 copy LDS -> global =======
    float* __restrict__ dV = oV + (size_t)blockBase * 57;
#pragma unroll 1
    for (int s = 0; s < 4; ++s) {
        const int c0 = s * CSUB;
        int ch = vc - c0;                        // cells in this sub-phase
        ch = ch < 0 ? 0 : (ch > CSUB ? CSUB : ch);
        const int nU = ch * NE;                  // <= 1216

        // ---- compute: one edge-unit per lane-iteration ----
#pragma unroll 2
        for (int rr = 0; rr < 5; ++rr) {
            const int u = tid + (rr << 8);
            if (u < nU) {
                const unsigned cl = (unsigned)u / 19u;     // local cell
                const unsigned e  = (unsigned)u - cl * 19u;
                const unsigned c  = (unsigned)c0 + cl;     // block-local cell
                const float* Ld = state + c * LSTR;
                const unsigned meta = __float_as_uint(Ld[9]);
                const unsigned ii = meta & 127u;
                const unsigned jj = (meta >> 7) & 127u;
                const unsigned kk = (meta >> 14) & 127u;
                const unsigned a = (unsigned)(EAP >> (3u * e)) & 7u;
                const unsigned b = (unsigned)(EBP >> (3u * e)) & 7u;
                const float sa = Ld[a], sb = Ld[b];
                const bool cross = (sa < 0.0f) != (sb < 0.0f);
                const float t = cross ? sa / (sa - sb) : 0.0f;

                // verts: direct strided store (23% of bytes)
                const float pax = (float)(int)(ii + (a & 1u));
                const float pbx = (float)(int)(ii + (b & 1u));
                const float pay = (float)(int)(jj + ((a >> 1) & 1u));
                const float pby = (float)(int)(jj + ((b >> 1) & 1u));
                const float paz = (float)(int)(kk + ((a >> 2) & 1u));
                const float pbz = (float)(int)(kk + ((b >> 2) & 1u));
                const float vx = cross ? pax + t * (pbx - pax) : 0.0f;
                const float vy = cross ? pay + t * (pby - pay) : 0.0f;
                const float vz = cross ? paz + t * (pbz - paz) : 0.0f;
                const size_t vo = ((size_t)c * 19u + e) * 3u;
                dV[vo + 0] = (vx - 1.0f) * inv63;
                dV[vo + 1] = (vy - 1.0f) * inv63;
                dV[vo + 2] = (vz - 1.0f) * inv63;

                // feats -> LDS stage in global order
                const int xa = (int)ii + (int)(a & 1u) - 1;
                const int ya = (int)jj + (int)((a >> 1) & 1u) - 1;
                const int za = (int)kk + (int)((a >> 2) & 1u) - 1;
                const int xb = (int)ii + (int)(b & 1u) - 1;
                const int yb = (int)jj + (int)((b >> 1) & 1u) - 1;
                const int zb = (int)kk + (int)((b >> 2) & 1u) - 1;
                const bool iba = ((unsigned)xa < 64u) & ((unsigned)ya < 64u) & ((unsigned)za < 64u);
                const bool ibb = ((unsigned)xb < 64u) & ((unsigned)yb < 64u) & ((unsigned)zb < 64u);
                float4 fa0 = make_float4(0.f, 0.f, 0.f, 0.f), fa1 = fa0;
                float4 fb0 = fa0, fb1 = fa0;
                if (iba) {
                    const float4* fp = (const float4*)(feat + (size_t)((xa * 64 + ya) * 64 + za) * NF);
                    fa0 = fp[0]; fa1 = fp[1];
                }
                if (ibb) {
                    const float4* fp = (const float4*)(feat + (size_t)((xb * 64 + yb) * 64 + zb) * NF);
                    fb0 = fp[0]; fb1 = fp[1];
                }
                float4u flo, fhi;
                flo.x = cross ? fa0.x + t * (fb0.x - fa0.x) : 0.0f;
                flo.y = cross ? fa0.y + t * (fb0.y - fa0.y) : 0.0f;
                flo.z = cross ? fa0.z + t * (fb0.z - fa0.z) : 0.0f;
                flo.w = cross ? fa0.w + t * (fb0.w - fa0.w) : 0.0f;
                fhi.x = cross ? fa1.x + t * (fb1.x - fa1.x) : 0.0f;
                fhi.y = cross ? fa1.y + t * (fb1.y - fa1.y) : 0.0f;
                fhi.z = cross ? fa1.z + t * (fb1.z - fa1.z) : 0.0f;
                fhi.w = cross ? fa1.w + t * (fb1.w - fa1.w) : 0.0f;
                stage4[2 * u]     = flo;
                stage4[2 * u + 1] = fhi;
            }
        }
        __syncthreads();

        // ---- dense copy: lane p -> contiguous float4 p of this sub-phase ----
        {
            const int nd4 = ch * 38;            // <= 2432 float4s
            float4u* __restrict__ dF4 = (float4u*)(oF + ((size_t)blockBase + c0) * 152);
#pragma unroll 2
            for (int rr = 0; rr < 10; ++rr) {
                const int p = tid + (rr << 8);
                if (p < nd4) dF4[p] = stage4[p];
            }
        }
        __syncthreads();
    }

    // ---------------- tris: 6 guarded iterations (direct) ----------------
    {
        const int nT = vc * 6;
        float* __restrict__ dT = oT + (size_t)blockBase * 36;
#pragma unroll 2
        for (int rr = 0; rr < 6; ++rr) {
            const int T = tid + (rr << 8);
            if (T < nT) {
                const unsigned c  = (unsigned)T / 6u;
                const unsigned ti = (unsigned)T - c * 6u;
                const unsigned ins = __float_as_uint(state[c * LSTR + 8]);
                const unsigned tc = (unsigned)(TETP >> (6u * ti)) & 63u;
                const unsigned c1 = tc & 7u, c2 = tc >> 3;
                const unsigned cse = (ins & 1u)
                                   | (((ins >> c1) & 1u) << 1)
                                   | (((ins >> c2) & 1u) << 2)
                                   | (((ins >> 7) & 1u) << 3);
                const unsigned m  = MTP[cse];
                const unsigned tp = T2CPc[ti];
                const int cell19 = (blockBase + (int)c) * 19;
                float v6[6];
#pragma unroll
                for (int v = 0; v < 6; ++v) {
                    const unsigned lt = (m >> (4 * v)) & 0xFu;
                    const unsigned lc = (lt == 15u) ? 0u : lt;
                    const unsigned ce = (tp >> (5 * lc)) & 31u;
                    v6[v] = (lt == 15u) ? -1.0f : (float)(cell19 + (int)ce);
                }
                const size_t to = (size_t)T * 6u;
                float4u q0; q0.x = v6[0]; q0.y = v6[1]; q0.z = v6[2]; q0.w = v6[3];
                float2u q1; q1.x = v6[4]; q1.y = v6[5];
                *(float4u*)(dT + to)     = q0;
                *(float2u*)(dT + to + 4) = q1;
            }
        }
    }
}

extern "C" void kernel_launch(void* const* d_in, const int* in_sizes, int n_in,
                              void* d_out, int out_size, void* d_ws, size_t ws_size,
                              hipStream_t stream) {
    const float* sdf  = (const float*)d_in[0];
    const float* feat = (const float*)d_in[1];
    float* out = (float*)d_out;
    float* oV = out;
    float* oF = oV + (size_t)NCELL * NE * 3;
    float* oT = oF + (size_t)NCELL * NE * NF;
    int blocks = (NCELL + 255) / 256;
    diffmc_kernel<<<blocks, 256, 0, stream>>>(sdf, feat, oV, oF, oT);
}

// Round 10
// 53.208 us; speedup vs baseline: 2.2238x; 1.1661x over previous
//
#include <hip/hip_runtime.h>

#define NC 65
#define NCELL 274625
#define NE 19
#define NF 8
#define LSTR 11    // per-cell state: [0..7]=sdf corners, [8]=ins, [9]=ijk, [10] pad
#define NB 1073    // blocks per role

// MT_TRI rows packed 4 bits per entry (0xF == -1), entry v at bits [4v,4v+4)
__constant__ unsigned MTP[16] = {
    0x00FFFFFFu, 0x00FFF210u, 0x00FFF430u, 0x00341421u,
    0x00FFF531u, 0x00350520u, 0x00450510u, 0x00FFF542u,
    0x00FFF542u, 0x00450510u, 0x00250530u, 0x00FFF531u,
    0x00241431u, 0x00FFF430u, 0x00FFF210u, 0x00FFFFFFu
};
// T2C rows packed 5 bits per entry: entry e at bits [5e,5e+5)
__constant__ unsigned T2CPc[6] = {
    0x0A418820u, 0x105388C1u, 0x16850926u,
    0x1CB68989u, 0x22E809ECu, 0x0919080Fu
};
// cell-edge endpoints (reference discovery order)
__device__ constexpr int EA[NE] = {0,0,0,1,1,3,0,2,2,0,2,6,0,4,4,0,4,5,1};
__device__ constexpr int EB[NE] = {1,3,7,3,7,7,2,3,7,6,6,7,4,6,7,5,5,7,5};
// Bit-packed (3 bits per edge); verified entry-by-entry.
#define EAP 0x006C120C82419200ULL
#define EBP 0x017DBF4FB76BF7D9ULL
// Tets: corner0=0, corner3=7 for all tets; (c1 | c2<<3) at bits [6ti,6ti+6)
#define TETP 0x36C9B24D9ULL

typedef float float4u __attribute__((ext_vector_type(4), aligned(4)));
typedef float float2u __attribute__((ext_vector_type(2), aligned(4)));

extern "C" __global__ void __launch_bounds__(256, 4)
diffmc_kernel(const float* __restrict__ sdf, const float* __restrict__ feat,
              float* __restrict__ oV, float* __restrict__ oF, float* __restrict__ oT)
{
    __shared__ float state[256 * LSTR];   // 11264 B
    const int tid = threadIdx.x;
    // role 0 = feats (62% of bytes, dispatched first), 1 = verts, 2 = tris
    const int role = blockIdx.x < NB ? 0 : (blockIdx.x < 2 * NB ? 1 : 2);
    const int rbid = blockIdx.x - role * NB;
    const int blockBase = rbid << 8;
    int vc = NCELL - blockBase;
    vc = vc > 256 ? 256 : vc;

    // ---------------- phase 0: per-cell corner sdf + meta ----------------
    if (tid < vc) {
        const int cell = blockBase + tid;
        const int k  = cell % NC;
        const int t_ = cell / NC;
        const int j  = t_ % NC;
        const int i  = t_ / NC;
        float cs[8];
#pragma unroll
        for (int c = 0; c < 8; ++c) {
            int x = i + (c & 1) - 1;
            int y = j + ((c >> 1) & 1) - 1;
            int z = k + ((c >> 2) & 1) - 1;
            bool inb = ((unsigned)x < 64u) & ((unsigned)y < 64u) & ((unsigned)z < 64u);
            cs[c] = inb ? sdf[(x * 64 + y) * 64 + z] : 1.0f;   // pad = iso + 1
        }
        unsigned ins = 0;
#pragma unroll
        for (int c = 0; c < 8; ++c) ins |= (cs[c] < 0.0f ? 1u : 0u) << c;
        float* Ld = state + tid * LSTR;
#pragma unroll
        for (int c = 0; c < 8; ++c) Ld[c] = cs[c];
        Ld[8] = __uint_as_float(ins);
        Ld[9] = __uint_as_float((unsigned)i | ((unsigned)j << 7) | ((unsigned)k << 14));
    }
    __syncthreads();

    const float inv63 = 1.0f / 63.0f;

    if (role == 0) {
        // ================= feats only =================
        const int nE = vc * NE;
        float* __restrict__ dF = oF + (size_t)blockBase * 152;
#pragma unroll 2
        for (int rr = 0; rr < 19; ++rr) {
            const int E = tid + (rr << 8);
            if (E < nE) {
                const unsigned c = (unsigned)E / 19u;
                const unsigned e = (unsigned)E - c * 19u;
                const float* Ld = state + c * LSTR;
                const unsigned meta = __float_as_uint(Ld[9]);
                const int ii = (int)(meta & 127u);
                const int jj = (int)((meta >> 7) & 127u);
                const int kk = (int)((meta >> 14) & 127u);
                const unsigned a = (unsigned)(EAP >> (3u * e)) & 7u;
                const unsigned b = (unsigned)(EBP >> (3u * e)) & 7u;
                const float sa = Ld[a], sb = Ld[b];
                const bool cross = (sa < 0.0f) != (sb < 0.0f);
                const float t = cross ? sa / (sa - sb) : 0.0f;

                const int xa = ii + (int)(a & 1u) - 1;
                const int ya = jj + (int)((a >> 1) & 1u) - 1;
                const int za = kk + (int)((a >> 2) & 1u) - 1;
                const int xb = ii + (int)(b & 1u) - 1;
                const int yb = jj + (int)((b >> 1) & 1u) - 1;
                const int zb = kk + (int)((b >> 2) & 1u) - 1;
                const bool iba = ((unsigned)xa < 64u) & ((unsigned)ya < 64u) & ((unsigned)za < 64u);
                const bool ibb = ((unsigned)xb < 64u) & ((unsigned)yb < 64u) & ((unsigned)zb < 64u);
                float4 fa0 = make_float4(0.f, 0.f, 0.f, 0.f), fa1 = fa0;
                float4 fb0 = fa0, fb1 = fa0;
                if (iba) {
                    const float4* fp = (const float4*)(feat + (size_t)((xa * 64 + ya) * 64 + za) * NF);
                    fa0 = fp[0]; fa1 = fp[1];
                }
                if (ibb) {
                    const float4* fp = (const float4*)(feat + (size_t)((xb * 64 + yb) * 64 + zb) * NF);
                    fb0 = fp[0]; fb1 = fp[1];
                }
                float4u flo, fhi;
                flo.x = cross ? fa0.x + t * (fb0.x - fa0.x) : 0.0f;
                flo.y = cross ? fa0.y + t * (fb0.y - fa0.y) : 0.0f;
                flo.z = cross ? fa0.z + t * (fb0.z - fa0.z) : 0.0f;
                flo.w = cross ? fa0.w + t * (fb0.w - fa0.w) : 0.0f;
                fhi.x = cross ? fa1.x + t * (fb1.x - fa1.x) : 0.0f;
                fhi.y = cross ? fa1.y + t * (fb1.y - fa1.y) : 0.0f;
                fhi.z = cross ? fa1.z + t * (fb1.z - fa1.z) : 0.0f;
                fhi.w = cross ? fa1.w + t * (fb1.w - fa1.w) : 0.0f;
                const size_t fo = (size_t)E * 8u;
                *(float4u*)(dF + fo)     = flo;
                *(float4u*)(dF + fo + 4) = fhi;
            }
        }
    } else if (role == 1) {
        // ================= verts only =================
        const int nE = vc * NE;
        float* __restrict__ dV = oV + (size_t)blockBase * 57;
#pragma unroll 2
        for (int rr = 0; rr < 19; ++rr) {
            const int E = tid + (rr << 8);
            if (E < nE) {
                const unsigned c = (unsigned)E / 19u;
                const unsigned e = (unsigned)E - c * 19u;
                const float* Ld = state + c * LSTR;
                const unsigned meta = __float_as_uint(Ld[9]);
                const unsigned ii = meta & 127u;
                const unsigned jj = (meta >> 7) & 127u;
                const unsigned kk = (meta >> 14) & 127u;
                const unsigned a = (unsigned)(EAP >> (3u * e)) & 7u;
                const unsigned b = (unsigned)(EBP >> (3u * e)) & 7u;
                const float sa = Ld[a], sb = Ld[b];
                const bool cross = (sa < 0.0f) != (sb < 0.0f);
                const float t = cross ? sa / (sa - sb) : 0.0f;

                const float pax = (float)(int)(ii + (a & 1u));
                const float pbx = (float)(int)(ii + (b & 1u));
                const float pay = (float)(int)(jj + ((a >> 1) & 1u));
                const float pby = (float)(int)(jj + ((b >> 1) & 1u));
                const float paz = (float)(int)(kk + ((a >> 2) & 1u));
                const float pbz = (float)(int)(kk + ((b >> 2) & 1u));
                const float vx = cross ? pax + t * (pbx - pax) : 0.0f;
                const float vy = cross ? pay + t * (pby - pay) : 0.0f;
                const float vz = cross ? paz + t * (pbz - paz) : 0.0f;
                const size_t vo = (size_t)E * 3u;
                dV[vo + 0] = (vx - 1.0f) * inv63;
                dV[vo + 1] = (vy - 1.0f) * inv63;
                dV[vo + 2] = (vz - 1.0f) * inv63;
            }
        }
    } else {
        // ================= tris only =================
        const int nT = vc * 6;
        float* __restrict__ dT = oT + (size_t)blockBase * 36;
#pragma unroll 2
        for (int rr = 0; rr < 6; ++rr) {
            const int T = tid + (rr << 8);
            if (T < nT) {
                const unsigned c  = (unsigned)T / 6u;
                const unsigned ti = (unsigned)T - c * 6u;
                const unsigned ins = __float_as_uint(state[c * LSTR + 8]);
                const unsigned tc = (unsigned)(TETP >> (6u * ti)) & 63u;
                const unsigned c1 = tc & 7u, c2 = tc >> 3;
                const unsigned cse = (ins & 1u)
                                   | (((ins >> c1) & 1u) << 1)
                                   | (((ins >> c2) & 1u) << 2)
                                   | (((ins >> 7) & 1u) << 3);
                const unsigned m  = MTP[cse];
                const unsigned tp = T2CPc[ti];
                const int cell19 = (blockBase + (int)c) * 19;
                float v6[6];
#pragma unroll
                for (int v = 0; v < 6; ++v) {
                    const unsigned lt = (m >> (4 * v)) & 0xFu;
                    const unsigned lc = (lt == 15u) ? 0u : lt;
                    const unsigned ce = (tp >> (5 * lc)) & 31u;
                    v6[v] = (lt == 15u) ? -1.0f : (float)(cell19 + (int)ce);
                }
                const size_t to = (size_t)T * 6u;
                float4u q0; q0.x = v6[0]; q0.y = v6[1]; q0.z = v6[2]; q0.w = v6[3];
                float2u q1; q1.x = v6[4]; q1.y = v6[5];
                *(float4u*)(dT + to)     = q0;
                *(float2u*)(dT + to + 4) = q1;
            }
        }
    }
}

extern "C" void kernel_launch(void* const* d_in, const int* in_sizes, int n_in,
                              void* d_out, int out_size, void* d_ws, size_t ws_size,
                              hipStream_t stream) {
    const float* sdf  = (const float*)d_in[0];
    const float* feat = (const float*)d_in[1];
    float* out = (float*)d_out;
    float* oV = out;
    float* oF = oV + (size_t)NCELL * NE * 3;
    float* oT = oF + (size_t)NCELL * NE * NF;
    diffmc_kernel<<<3 * NB, 256, 0, stream>>>(sdf, feat, oV, oF, oT);
}

// Round 11
// 53.155 us; speedup vs baseline: 2.2260x; 1.0010x over previous
//
#include <hip/hip_runtime.h>

#define NC 65
#define NCELL 274625
#define NE 19
#define NF 8
#define LSTR 11    // per-cell state: [0..7]=sdf corners, [8]=ins, [9]=ijk, [10] pad
#define NB 1073    // blocks per role

// MT_TRI rows packed 4 bits per entry (0xF == -1), entry v at bits [4v,4v+4)
__constant__ unsigned MTP[16] = {
    0x00FFFFFFu, 0x00FFF210u, 0x00FFF430u, 0x00341421u,
    0x00FFF531u, 0x00350520u, 0x00450510u, 0x00FFF542u,
    0x00FFF542u, 0x00450510u, 0x00250530u, 0x00FFF531u,
    0x00241431u, 0x00FFF430u, 0x00FFF210u, 0x00FFFFFFu
};
// T2C rows packed 5 bits per entry: entry e at bits [5e,5e+5)
__constant__ unsigned T2CPc[6] = {
    0x0A418820u, 0x105388C1u, 0x16850926u,
    0x1CB68989u, 0x22E809ECu, 0x0919080Fu
};
// cell-edge endpoints (reference discovery order)
__device__ constexpr int EA[NE] = {0,0,0,1,1,3,0,2,2,0,2,6,0,4,4,0,4,5,1};
__device__ constexpr int EB[NE] = {1,3,7,3,7,7,2,3,7,6,6,7,4,6,7,5,5,7,5};
// Bit-packed (3 bits per edge); verified entry-by-entry.
#define EAP 0x006C120C82419200ULL
#define EBP 0x017DBF4FB76BF7D9ULL
// Tets: corner0=0, corner3=7 for all tets; (c1 | c2<<3) at bits [6ti,6ti+6)
#define TETP 0x36C9B24D9ULL

typedef float float4u __attribute__((ext_vector_type(4), aligned(4)));
typedef float float2u __attribute__((ext_vector_type(2), aligned(4)));

extern "C" __global__ void __launch_bounds__(256, 4)
diffmc_kernel(const float* __restrict__ sdf, const float* __restrict__ feat,
              float* __restrict__ oV, float* __restrict__ oF, float* __restrict__ oT)
{
    __shared__ float state[256 * LSTR];   // 11264 B
    const int tid = threadIdx.x;
    // role 0 = feats (62% of bytes, dispatched first), 1 = verts, 2 = tris
    const int role = blockIdx.x < NB ? 0 : (blockIdx.x < 2 * NB ? 1 : 2);
    const int rorig = blockIdx.x - role * NB;

    // bijective chunked XCD swizzle within the role (nwg=1073: q=134, r=1).
    // XCD x owns a contiguous rbid range -> contiguous write chunk + L2-resident
    // feat slab per XCD.
    const int xcd = rorig & 7, sidx = rorig >> 3;
    const int rbid = (xcd < 1 ? xcd * 135 : 135 + (xcd - 1) * 134) + sidx;

    const int blockBase = rbid << 8;
    int vc = NCELL - blockBase;
    vc = vc > 256 ? 256 : vc;

    // ---------------- phase 0: per-cell corner sdf + meta ----------------
    if (tid < vc) {
        const int cell = blockBase + tid;
        const int k  = cell % NC;
        const int t_ = cell / NC;
        const int j  = t_ % NC;
        const int i  = t_ / NC;
        float cs[8];
#pragma unroll
        for (int c = 0; c < 8; ++c) {
            int x = i + (c & 1) - 1;
            int y = j + ((c >> 1) & 1) - 1;
            int z = k + ((c >> 2) & 1) - 1;
            bool inb = ((unsigned)x < 64u) & ((unsigned)y < 64u) & ((unsigned)z < 64u);
            cs[c] = inb ? sdf[(x * 64 + y) * 64 + z] : 1.0f;   // pad = iso + 1
        }
        unsigned ins = 0;
#pragma unroll
        for (int c = 0; c < 8; ++c) ins |= (cs[c] < 0.0f ? 1u : 0u) << c;
        float* Ld = state + tid * LSTR;
#pragma unroll
        for (int c = 0; c < 8; ++c) Ld[c] = cs[c];
        Ld[8] = __uint_as_float(ins);
        Ld[9] = __uint_as_float((unsigned)i | ((unsigned)j << 7) | ((unsigned)k << 14));
    }
    __syncthreads();

    const float inv63 = 1.0f / 63.0f;

    if (role == 0) {
        // ================= feats only =================
        const int nE = vc * NE;
        float* __restrict__ dF = oF + (size_t)blockBase * 152;
#pragma unroll 2
        for (int rr = 0; rr < 19; ++rr) {
            const int E = tid + (rr << 8);
            if (E < nE) {
                const unsigned c = (unsigned)E / 19u;
                const unsigned e = (unsigned)E - c * 19u;
                const float* Ld = state + c * LSTR;
                const unsigned meta = __float_as_uint(Ld[9]);
                const int ii = (int)(meta & 127u);
                const int jj = (int)((meta >> 7) & 127u);
                const int kk = (int)((meta >> 14) & 127u);
                const unsigned a = (unsigned)(EAP >> (3u * e)) & 7u;
                const unsigned b = (unsigned)(EBP >> (3u * e)) & 7u;
                const float sa = Ld[a], sb = Ld[b];
                const bool cross = (sa < 0.0f) != (sb < 0.0f);
                const float t = cross ? sa / (sa - sb) : 0.0f;

                const int xa = ii + (int)(a & 1u) - 1;
                const int ya = jj + (int)((a >> 1) & 1u) - 1;
                const int za = kk + (int)((a >> 2) & 1u) - 1;
                const int xb = ii + (int)(b & 1u) - 1;
                const int yb = jj + (int)((b >> 1) & 1u) - 1;
                const int zb = kk + (int)((b >> 2) & 1u) - 1;
                const bool iba = ((unsigned)xa < 64u) & ((unsigned)ya < 64u) & ((unsigned)za < 64u);
                const bool ibb = ((unsigned)xb < 64u) & ((unsigned)yb < 64u) & ((unsigned)zb < 64u);
                float4 fa0 = make_float4(0.f, 0.f, 0.f, 0.f), fa1 = fa0;
                float4 fb0 = fa0, fb1 = fa0;
                if (iba) {
                    const float4* fp = (const float4*)(feat + (size_t)((xa * 64 + ya) * 64 + za) * NF);
                    fa0 = fp[0]; fa1 = fp[1];
                }
                if (ibb) {
                    const float4* fp = (const float4*)(feat + (size_t)((xb * 64 + yb) * 64 + zb) * NF);
                    fb0 = fp[0]; fb1 = fp[1];
                }
                float4u flo, fhi;
                flo.x = cross ? fa0.x + t * (fb0.x - fa0.x) : 0.0f;
                flo.y = cross ? fa0.y + t * (fb0.y - fa0.y) : 0.0f;
                flo.z = cross ? fa0.z + t * (fb0.z - fa0.z) : 0.0f;
                flo.w = cross ? fa0.w + t * (fb0.w - fa0.w) : 0.0f;
                fhi.x = cross ? fa1.x + t * (fb1.x - fa1.x) : 0.0f;
                fhi.y = cross ? fa1.y + t * (fb1.y - fa1.y) : 0.0f;
                fhi.z = cross ? fa1.z + t * (fb1.z - fa1.z) : 0.0f;
                fhi.w = cross ? fa1.w + t * (fb1.w - fa1.w) : 0.0f;
                const size_t fo = (size_t)E * 8u;
                *(float4u*)(dF + fo)     = flo;
                *(float4u*)(dF + fo + 4) = fhi;
            }
        }
    } else if (role == 1) {
        // ================= verts only =================
        const int nE = vc * NE;
        float* __restrict__ dV = oV + (size_t)blockBase * 57;
#pragma unroll 2
        for (int rr = 0; rr < 19; ++rr) {
            const int E = tid + (rr << 8);
            if (E < nE) {
                const unsigned c = (unsigned)E / 19u;
                const unsigned e = (unsigned)E - c * 19u;
                const float* Ld = state + c * LSTR;
                const unsigned meta = __float_as_uint(Ld[9]);
                const unsigned ii = meta & 127u;
                const unsigned jj = (meta >> 7) & 127u;
                const unsigned kk = (meta >> 14) & 127u;
                const unsigned a = (unsigned)(EAP >> (3u * e)) & 7u;
                const unsigned b = (unsigned)(EBP >> (3u * e)) & 7u;
                const float sa = Ld[a], sb = Ld[b];
                const bool cross = (sa < 0.0f) != (sb < 0.0f);
                const float t = cross ? sa / (sa - sb) : 0.0f;

                const float pax = (float)(int)(ii + (a & 1u));
                const float pbx = (float)(int)(ii + (b & 1u));
                const float pay = (float)(int)(jj + ((a >> 1) & 1u));
                const float pby = (float)(int)(jj + ((b >> 1) & 1u));
                const float paz = (float)(int)(kk + ((a >> 2) & 1u));
                const float pbz = (float)(int)(kk + ((b >> 2) & 1u));
                const float vx = cross ? pax + t * (pbx - pax) : 0.0f;
                const float vy = cross ? pay + t * (pby - pay) : 0.0f;
                const float vz = cross ? paz + t * (pbz - paz) : 0.0f;
                const size_t vo = (size_t)E * 3u;
                dV[vo + 0] = (vx - 1.0f) * inv63;
                dV[vo + 1] = (vy - 1.0f) * inv63;
                dV[vo + 2] = (vz - 1.0f) * inv63;
            }
        }
    } else {
        // ================= tris only =================
        const int nT = vc * 6;
        float* __restrict__ dT = oT + (size_t)blockBase * 36;
#pragma unroll 2
        for (int rr = 0; rr < 6; ++rr) {
            const int T = tid + (rr << 8);
            if (T < nT) {
                const unsigned c  = (unsigned)T / 6u;
                const unsigned ti = (unsigned)T - c * 6u;
                const unsigned ins = __float_as_uint(state[c * LSTR + 8]);
                const unsigned tc = (unsigned)(TETP >> (6u * ti)) & 63u;
                const unsigned c1 = tc & 7u, c2 = tc >> 3;
                const unsigned cse = (ins & 1u)
                                   | (((ins >> c1) & 1u) << 1)
                                   | (((ins >> c2) & 1u) << 2)
                                   | (((ins >> 7) & 1u) << 3);
                const unsigned m  = MTP[cse];
                const unsigned tp = T2CPc[ti];
                const int cell19 = (blockBase + (int)c) * 19;
                float v6[6];
#pragma unroll
                for (int v = 0; v < 6; ++v) {
                    const unsigned lt = (m >> (4 * v)) & 0xFu;
                    const unsigned lc = (lt == 15u) ? 0u : lt;
                    const unsigned ce = (tp >> (5 * lc)) & 31u;
                    v6[v] = (lt == 15u) ? -1.0f : (float)(cell19 + (int)ce);
                }
                const size_t to = (size_t)T * 6u;
                float4u q0; q0.x = v6[0]; q0.y = v6[1]; q0.z = v6[2]; q0.w = v6[3];
                float2u q1; q1.x = v6[4]; q1.y = v6[5];
                *(float4u*)(dT + to)     = q0;
                *(float2u*)(dT + to + 4) = q1;
            }
        }
    }
}

extern "C" void kernel_launch(void* const* d_in, const int* in_sizes, int n_in,
                              void* d_out, int out_size, void* d_ws, size_t ws_size,
                              hipStream_t stream) {
    const float* sdf  = (const float*)d_in[0];
    const float* feat = (const float*)d_in[1];
    float* out = (float*)d_out;
    float* oV = out;
    float* oF = oV + (size_t)NCELL * NE * 3;
    float* oT = oF + (size_t)NCELL * NE * NF;
    diffmc_kernel<<<3 * NB, 256, 0, stream>>>(sdf, feat, oV, oF, oT);
}